// Round 9
// baseline (135.333 us; speedup 1.0000x reference)
//
#include <hip/hip_runtime.h>
#include <math.h>

#define EPSV 1e-6f
#define NSL  0.2f
#define BB   2
#define NN   2048
#define HH   8
#define TB   4

typedef short bf16x8 __attribute__((ext_vector_type(8)));
typedef float f32x4  __attribute__((ext_vector_type(4)));

__device__ __forceinline__ unsigned short f2bf(float x) {
  union { float f; unsigned int u; } v; v.f = x;
  unsigned int r = v.u + 0x7FFF + ((v.u >> 16) & 1);
  return (unsigned short)(r >> 16);
}
__device__ __forceinline__ float bf2f(unsigned short h) {
  union { float f; unsigned int u; } v; v.u = ((unsigned int)h) << 16;
  return v.f;
}
__device__ __forceinline__ unsigned cvt_pk_bf16(float a, float b) {
  unsigned r;
  asm("v_cvt_pk_bf16_f32 %0, %1, %2" : "=v"(r) : "v"(a), "v"(b));
  return r;
}
__device__ __forceinline__ float dot4(float4 x, const float* w) {
  return x.x * w[0] + x.y * w[1] + x.z * w[2] + x.w * w[3];
}

// Workspace fragment layouts (bf16 hi/lo planes):
// QW/KW per (hb, tile16): [hl 2][768]: c0=[lane64][8] @0, c1=[lane<32][8] @512
// VW per (hb, kc32, f):   [hl 2][512]: [lane64][8]

// ---------------------------------------------------------------------------
// pre: merged q/kv (blockIdx.y: 0=q, 1=kv). 4 tokens / 128 threads.
// Wave sub handles tokens t0+2sub..+1; thread jc owns channels jc and jc+64.
// Uniform operands (x, f) read from GLOBAL (L1-broadcast, off the LDS pipe);
// f round-trips through global scratch fg (aliases Obuf / d_out).
// Q scaled by 0.25*log2(e): softmax runs in exp2 domain.
// ---------------------------------------------------------------------------
__global__ __launch_bounds__(128) void pre_kernel(
    const float* __restrict__ qfts, const float* __restrict__ kvfts,
    const float* __restrict__ wq_in, const float* __restrict__ qw1, const float* __restrict__ qb1,
    const float* __restrict__ qw2, const float* __restrict__ qb2,
    const float* __restrict__ wkv_in, const float* __restrict__ kw1, const float* __restrict__ kb1,
    const float* __restrict__ kw2, const float* __restrict__ kb2,
    const float* __restrict__ w_q, const float* __restrict__ w_k, const float* __restrict__ w_v,
    float* __restrict__ fg_q, float* __restrict__ fg_kv,
    unsigned short* __restrict__ QW, unsigned short* __restrict__ KW, unsigned short* __restrict__ VW)
{
  const bool is_kv = blockIdx.y != 0;
  const float* x_in = is_kv ? kvfts : qfts;
  const float* w_in = is_kv ? wkv_in : wq_in;
  const float* w1   = is_kv ? kw1 : qw1;
  const float* b1   = is_kv ? kb1 : qb1;
  const float* w2   = is_kv ? kw2 : qw2;
  const float* b2   = is_kv ? kb2 : qb2;
  const float* w_p  = is_kv ? w_k : w_q;
  float* fg = is_kv ? fg_kv : fg_q;
  unsigned short* FW = is_kv ? KW : QW;
  const float ln_sc = is_kv ? 1.f : 0.25f * 1.44269504088896f;

  const int t0 = blockIdx.x * TB;
  const int tid = threadIdx.x;
  const int sub = tid >> 6;      // wave index: tokens t0+2sub, t0+2sub+1
  const int jc  = tid & 63;      // channels jc and jc+64
  const int tokA = t0 + sub * 2;

  __shared__ float norm_s[TB][128];
  __shared__ float h_s[TB][64];

  // ---- phase 1: input GEMM (x uniform from global) ----
  float pA[2][3] = {{0}}, pB[2][3] = {{0}};
  #pragma unroll 2
  for (int c = 0; c < 64; c += 4) {
    float wA[4], wB[4];
    #pragma unroll
    for (int i = 0; i < 4; ++i) {
      wA[i] = w_in[(c + i) * 128 + jc];
      wB[i] = w_in[(c + i) * 128 + jc + 64];
    }
    #pragma unroll
    for (int t = 0; t < 2; ++t)
      #pragma unroll
      for (int f = 0; f < 3; ++f) {
        float4 xv = *(const float4*)(x_in + (size_t)(tokA + t) * 192 + f * 64 + c);
        pA[t][f] += dot4(xv, wA);
        pB[t][f] += dot4(xv, wB);
      }
  }

  // ---- phase 2: norms ----
  float npA[2], npB[2]; int zA = 0, zB = 0;
  #pragma unroll
  for (int t = 0; t < 2; ++t) {
    float nA = sqrtf(pA[t][0] * pA[t][0] + pA[t][1] * pA[t][1] + pA[t][2] * pA[t][2]);
    float nB = sqrtf(pB[t][0] * pB[t][0] + pB[t][1] * pB[t][1] + pB[t][2] * pB[t][2]);
    if (nA <= EPSV) zA |= 1 << t;
    if (nB <= EPSV) zB |= 1 << t;
    npA[t] = nA + EPSV; npB[t] = nB + EPSV;
    norm_s[sub * 2 + t][jc] = npA[t];
    norm_s[sub * 2 + t][jc + 64] = npB[t];
  }
  __syncthreads();

  // ---- phase 3: MLP1 (128->64), thread computes h[own 2 tokens][jc] ----
  float a2[2];
  { float bb = b1[jc]; a2[0] = bb; a2[1] = bb; }
  #pragma unroll 2
  for (int c = 0; c < 128; c += 4) {
    float w4[4];
    #pragma unroll
    for (int i = 0; i < 4; ++i) w4[i] = w1[(c + i) * 64 + jc];
    #pragma unroll
    for (int t = 0; t < 2; ++t) {
      float4 n4 = *(const float4*)&norm_s[sub * 2 + t][c];
      a2[t] += dot4(n4, w4);
    }
  }
  #pragma unroll
  for (int t = 0; t < 2; ++t)
    h_s[sub * 2 + t][jc] = a2[t] > 0.f ? a2[t] : NSL * a2[t];
  __syncthreads();

  // ---- phase 4: MLP2 (64->128) ----
  float bnA[2], bnB[2];
  {
    float bA = b2[jc], bB = b2[jc + 64];
    #pragma unroll
    for (int t = 0; t < 2; ++t) { bnA[t] = bA + npA[t]; bnB[t] = bB + npB[t]; }
  }
  #pragma unroll 2
  for (int c = 0; c < 64; c += 4) {
    float wA[4], wB[4];
    #pragma unroll
    for (int i = 0; i < 4; ++i) {
      wA[i] = w2[(c + i) * 128 + jc];
      wB[i] = w2[(c + i) * 128 + jc + 64];
    }
    #pragma unroll
    for (int t = 0; t < 2; ++t) {
      float4 h4 = *(const float4*)&h_s[sub * 2 + t][c];
      bnA[t] += dot4(h4, wA);
      bnB[t] += dot4(h4, wB);
    }
  }

  // ---- phase 5: ratio; write f to global scratch ----
  #pragma unroll
  for (int t = 0; t < 2; ++t) {
    float rA = (zA >> t) & 1 ? 1.f : bnA[t] / npA[t];
    float rB = (zB >> t) & 1 ? 1.f : bnB[t] / npB[t];
    float* fb = fg + (size_t)(tokA + t) * 384;
    #pragma unroll
    for (int f = 0; f < 3; ++f) {
      fb[f * 128 + jc]      = pA[t][f] * rA;
      fb[f * 128 + jc + 64] = pB[t][f] * rB;
    }
  }
  __threadfence_block();
  __syncthreads();

  // ---- phase 6..9: projections (f uniform from global) + writes ----
  const int dd = jc & 15;
  const int hhA = jc >> 4, hhB = 4 + (jc >> 4);

  float qA[2][3] = {{0}}, qB[2][3] = {{0}};
  float vA[2][3] = {{0}}, vB[2][3] = {{0}};
  #pragma unroll 1
  for (int c = 0; c < 128; c += 4) {
    float wkA[4], wkB[4], wvA[4], wvB[4];
    #pragma unroll
    for (int i = 0; i < 4; ++i) {
      wkA[i] = w_p[(c + i) * 128 + jc];
      wkB[i] = w_p[(c + i) * 128 + jc + 64];
      if (is_kv) {
        wvA[i] = w_v[(c + i) * 128 + jc];
        wvB[i] = w_v[(c + i) * 128 + jc + 64];
      }
    }
    #pragma unroll
    for (int t = 0; t < 2; ++t)
      #pragma unroll
      for (int f = 0; f < 3; ++f) {
        float4 fv = *(const float4*)(fg + (size_t)(tokA + t) * 384 + f * 128 + c);
        qA[t][f] += dot4(fv, wkA);
        qB[t][f] += dot4(fv, wkB);
        if (is_kv) {
          vA[t][f] += dot4(fv, wvA);
          vB[t][f] += dot4(fv, wvB);
        }
      }
  }

  // EV layernorm (q/k) + fragment writes
  #pragma unroll
  for (int t = 0; t < 2; ++t) {
    float ssA = qA[t][0] * qA[t][0] + qA[t][1] * qA[t][1] + qA[t][2] * qA[t][2];
    float ssB = qB[t][0] * qB[t][0] + qB[t][1] * qB[t][1] + qB[t][2] * qB[t][2];
    ssA += __shfl_xor(ssA, 1, 16); ssB += __shfl_xor(ssB, 1, 16);
    ssA += __shfl_xor(ssA, 2, 16); ssB += __shfl_xor(ssB, 2, 16);
    ssA += __shfl_xor(ssA, 4, 16); ssB += __shfl_xor(ssB, 4, 16);
    ssA += __shfl_xor(ssA, 8, 16); ssB += __shfl_xor(ssB, 8, 16);
    float invA = ln_sc / (sqrtf(ssA * (1.f / 16.f)) + EPSV);
    float invB = ln_sc / (sqrtf(ssB * (1.f / 16.f)) + EPSV);

    const int tok = tokA + t;
    const int b = tok >> 11, n = tok & (NN - 1);
    const int row = n & 15;
    #pragma unroll
    for (int s = 0; s < 2; ++s) {
      const int hh = s ? hhB : hhA;
      const int hb = hh * BB + b;
      const size_t base = (size_t)(hb * 128 + (n >> 4)) * 1536;
      #pragma unroll
      for (int f = 0; f < 3; ++f) {
        float val = (s ? qB[t][f] * invB : qA[t][f] * invA);
        int d = f * 16 + dd;
        int off;
        if (d < 32) off = ((d >> 3) * 16 + row) * 8 + (d & 7);
        else        off = 512 + (((d - 32) >> 3) * 16 + row) * 8 + ((d - 32) & 7);
        unsigned short hi = f2bf(val);
        FW[base + off] = hi;
        FW[base + 768 + off] = f2bf(val - bf2f(hi));
      }
      if (is_kv) {
        const int voff = (((n & 31) >> 3) * 16 + dd) * 8 + (n & 7);
        #pragma unroll
        for (int f = 0; f < 3; ++f) {
          float val = (s ? vB[t][f] : vA[t][f]);
          const size_t vbase = (size_t)((hb * 64 + (n >> 5)) * 3 + f) * 1024;
          unsigned short hi = f2bf(val);
          VW[vbase + voff] = hi;
          VW[vbase + 512 + voff] = f2bf(val - bf2f(hi));
        }
      }
    }
  }
}

// ---------------------------------------------------------------------------
// attention: MFMA flash, 4-way K-split, 32 q per wave (unchanged from r7).
// ---------------------------------------------------------------------------
#define THR 10.0f

__global__ __launch_bounds__(512, 4) void attn_kernel(
    const unsigned short* __restrict__ QW, const unsigned short* __restrict__ KW,
    const unsigned short* __restrict__ VW, float* __restrict__ Ob)
{
  const int lane = threadIdx.x & 63;
  const int w = threadIdx.x >> 6;
  const int qt = w & 1;
  const int kq = w >> 1;
  const int hb = blockIdx.y;
  const int tA = blockIdx.x * 4 + qt * 2;
  const int q = lane & 15, g = lane >> 4;

  __shared__ unsigned short plds[8][2][1152];
  float* comb = (float*)plds;

  bf16x8 qh0[2], ql0[2], qh1[2], ql1[2];
  #pragma unroll
  for (int qs = 0; qs < 2; ++qs) {
    const size_t qbase = (size_t)(hb * 128 + tA + qs) * 1536;
    qh0[qs] = *(const bf16x8*)(QW + qbase + lane * 8);
    ql0[qs] = *(const bf16x8*)(QW + qbase + 768 + lane * 8);
    qh1[qs] = (bf16x8){0,0,0,0,0,0,0,0};
    ql1[qs] = (bf16x8){0,0,0,0,0,0,0,0};
    if (lane < 32) {
      qh1[qs] = *(const bf16x8*)(QW + qbase + 512 + lane * 8);
      ql1[qs] = *(const bf16x8*)(QW + qbase + 768 + 512 + lane * 8);
    }
  }

  f32x4 o[2][3];
  #pragma unroll
  for (int qs = 0; qs < 2; ++qs)
    #pragma unroll
    for (int f = 0; f < 3; ++f) o[qs][f] = (f32x4){0.f, 0.f, 0.f, 0.f};
  float m[2] = {-INFINITY, -INFINITY}, l[2] = {0.f, 0.f};

  for (int T = kq * 8; T < kq * 8 + 8; ++T) {
    f32x4 sc[2][4];
    __builtin_amdgcn_s_setprio(1);
    #pragma unroll
    for (int st = 0; st < 4; ++st) {
      const size_t kb = (size_t)(hb * 128 + T * 4 + st) * 1536;
      bf16x8 kh0 = *(const bf16x8*)(KW + kb + lane * 8);
      bf16x8 kl0 = *(const bf16x8*)(KW + kb + 768 + lane * 8);
      bf16x8 kh1 = *(const bf16x8*)(KW + kb + 512 + lane * 8);
      bf16x8 kl1 = *(const bf16x8*)(KW + kb + 768 + 512 + lane * 8);
      #pragma unroll
      for (int qs = 0; qs < 2; ++qs) {
        f32x4 a = {0.f, 0.f, 0.f, 0.f};
        a = __builtin_amdgcn_mfma_f32_16x16x32_bf16(kh0, qh0[qs], a, 0, 0, 0);
        a = __builtin_amdgcn_mfma_f32_16x16x32_bf16(kh0, ql0[qs], a, 0, 0, 0);
        a = __builtin_amdgcn_mfma_f32_16x16x32_bf16(kl0, qh0[qs], a, 0, 0, 0);
        a = __builtin_amdgcn_mfma_f32_16x16x32_bf16(kh1, qh1[qs], a, 0, 0, 0);
        a = __builtin_amdgcn_mfma_f32_16x16x32_bf16(kh1, ql1[qs], a, 0, 0, 0);
        a = __builtin_amdgcn_mfma_f32_16x16x32_bf16(kl1, qh1[qs], a, 0, 0, 0);
        sc[qs][st] = a;
      }
    }
    __builtin_amdgcn_s_setprio(0);

    #pragma unroll
    for (int qs = 0; qs < 2; ++qs) {
      float tm = sc[qs][0][0];
      #pragma unroll
      for (int st = 0; st < 4; ++st)
        #pragma unroll
        for (int r = 0; r < 4; ++r) tm = fmaxf(tm, sc[qs][st][r]);
      tm = fmaxf(tm, __shfl_xor(tm, 16));
      tm = fmaxf(tm, __shfl_xor(tm, 32));
      if (__any(tm > m[qs] + THR)) {
        float mnew = fmaxf(m[qs], tm);
        float scl = __builtin_amdgcn_exp2f(m[qs] - mnew);
        l[qs] *= scl;
        #pragma unroll
        for (int f = 0; f < 3; ++f) {
          o[qs][f][0] *= scl; o[qs][f][1] *= scl;
          o[qs][f][2] *= scl; o[qs][f][3] *= scl;
        }
        m[qs] = mnew;
      }
      float lp = 0.f;
      #pragma unroll
      for (int st = 0; st < 4; ++st) {
        float p0 = __builtin_amdgcn_exp2f(sc[qs][st][0] - m[qs]);
        float p1 = __builtin_amdgcn_exp2f(sc[qs][st][1] - m[qs]);
        float p2 = __builtin_amdgcn_exp2f(sc[qs][st][2] - m[qs]);
        float p3 = __builtin_amdgcn_exp2f(sc[qs][st][3] - m[qs]);
        lp += (p0 + p1) + (p2 + p3);
        uint2 uh = {cvt_pk_bf16(p0, p1), cvt_pk_bf16(p2, p3)};
        *(uint2*)&plds[w][qs][q * 72 + st * 16 + g * 4] = uh;
      }
      lp += __shfl_xor(lp, 16);
      lp += __shfl_xor(lp, 32);
      l[qs] += lp;
    }

    asm volatile("s_waitcnt lgkmcnt(0)" ::: "memory");

    __builtin_amdgcn_s_setprio(1);
    #pragma unroll
    for (int c = 0; c < 2; ++c) {
      const int kc = T * 2 + c;
      bf16x8 pb[2];
      #pragma unroll
      for (int qs = 0; qs < 2; ++qs)
        pb[qs] = *(const bf16x8*)&plds[w][qs][q * 72 + c * 32 + g * 8];
      #pragma unroll
      for (int f = 0; f < 3; ++f) {
        const size_t vb = (size_t)((hb * 64 + kc) * 3 + f) * 1024;
        bf16x8 vh = *(const bf16x8*)(VW + vb + lane * 8);
        bf16x8 vl = *(const bf16x8*)(VW + vb + 512 + lane * 8);
        #pragma unroll
        for (int qs = 0; qs < 2; ++qs) {
          o[qs][f] = __builtin_amdgcn_mfma_f32_16x16x32_bf16(vh, pb[qs], o[qs][f], 0, 0, 0);
          o[qs][f] = __builtin_amdgcn_mfma_f32_16x16x32_bf16(vl, pb[qs], o[qs][f], 0, 0, 0);
        }
      }
    }
    __builtin_amdgcn_s_setprio(0);
  }

  #define SLOT(qt_, qs_, r_) (comb + ((((qt_) * 2 + (qs_)) * 2 + (r_)) * 64 + lane) * 14)
  __syncthreads();
  if (kq & 1) {
    #pragma unroll
    for (int qs = 0; qs < 2; ++qs) {
      float* cb = SLOT(qt, qs, kq >> 1);
      #pragma unroll
      for (int f = 0; f < 3; ++f)
        #pragma unroll
        for (int r = 0; r < 4; ++r) cb[f * 4 + r] = o[qs][f][r];
      cb[12] = m[qs]; cb[13] = l[qs];
    }
  }
  __syncthreads();
  if (!(kq & 1)) {
    #pragma unroll
    for (int qs = 0; qs < 2; ++qs) {
      const float* cb = SLOT(qt, qs, kq >> 1);
      float m1 = cb[12], l1 = cb[13];
      float mn = fmaxf(m[qs], m1);
      float s0 = __builtin_amdgcn_exp2f(m[qs] - mn);
      float s1 = __builtin_amdgcn_exp2f(m1 - mn);
      l[qs] = l[qs] * s0 + l1 * s1;
      #pragma unroll
      for (int f = 0; f < 3; ++f)
        #pragma unroll
        for (int r = 0; r < 4; ++r)
          o[qs][f][r] = o[qs][f][r] * s0 + cb[f * 4 + r] * s1;
      m[qs] = mn;
    }
  }
  __syncthreads();
  if (kq == 2) {
    #pragma unroll
    for (int qs = 0; qs < 2; ++qs) {
      float* cb = SLOT(qt, qs, 1);
      #pragma unroll
      for (int f = 0; f < 3; ++f)
        #pragma unroll
        for (int r = 0; r < 4; ++r) cb[f * 4 + r] = o[qs][f][r];
      cb[12] = m[qs]; cb[13] = l[qs];
    }
  }
  __syncthreads();
  if (kq == 0) {
    const int h_ = hb >> 1, b_ = hb & 1;
    #pragma unroll
    for (int qs = 0; qs < 2; ++qs) {
      const float* cb = SLOT(qt, qs, 1);
      float m1 = cb[12], l1 = cb[13];
      float mn = fmaxf(m[qs], m1);
      float s0 = __builtin_amdgcn_exp2f(m[qs] - mn);
      float s1 = __builtin_amdgcn_exp2f(m1 - mn);
      float invl = 1.f / (l[qs] * s0 + l1 * s1);
      const int n = (tA + qs) * 16 + q;
      #pragma unroll
      for (int f = 0; f < 3; ++f) {
        float4 st4 = {(o[qs][f][0] * s0 + cb[f * 4 + 0] * s1) * invl,
                      (o[qs][f][1] * s0 + cb[f * 4 + 1] * s1) * invl,
                      (o[qs][f][2] * s0 + cb[f * 4 + 2] * s1) * invl,
                      (o[qs][f][3] * s0 + cb[f * 4 + 3] * s1) * invl};
        *(float4*)&Ob[(((size_t)(b_ * NN + n)) * 3 + f) * 128 + h_ * 16 + g * 4] = st4;
      }
    }
  }
  #undef SLOT
}

// ---------------------------------------------------------------------------
// out: ev_nonlin(resi @ w_out). Same uniform-global-operand structure as pre.
// ---------------------------------------------------------------------------
__global__ __launch_bounds__(128) void out_kernel(
    const float* __restrict__ Ob, const float* __restrict__ w_out,
    const float* __restrict__ w1, const float* __restrict__ b1,
    const float* __restrict__ w2, const float* __restrict__ b2,
    float* __restrict__ out)
{
  const int t0 = blockIdx.x * TB;
  const int tid = threadIdx.x;
  const int sub = tid >> 6;
  const int jc  = tid & 63;
  const int tokA = t0 + sub * 2;

  __shared__ float norm_s[TB][128];
  __shared__ float h_s[TB][64];

  // proj: resi @ w_out (resi uniform from global)
  float pA[2][3] = {{0}}, pB[2][3] = {{0}};
  #pragma unroll 2
  for (int c = 0; c < 128; c += 4) {
    float wA[4], wB[4];
    #pragma unroll
    for (int i = 0; i < 4; ++i) {
      wA[i] = w_out[(c + i) * 128 + jc];
      wB[i] = w_out[(c + i) * 128 + jc + 64];
    }
    #pragma unroll
    for (int t = 0; t < 2; ++t)
      #pragma unroll
      for (int f = 0; f < 3; ++f) {
        float4 rv = *(const float4*)(Ob + (size_t)(tokA + t) * 384 + f * 128 + c);
        pA[t][f] += dot4(rv, wA);
        pB[t][f] += dot4(rv, wB);
      }
  }

  float npA[2], npB[2]; int zA = 0, zB = 0;
  #pragma unroll
  for (int t = 0; t < 2; ++t) {
    float nA = sqrtf(pA[t][0] * pA[t][0] + pA[t][1] * pA[t][1] + pA[t][2] * pA[t][2]);
    float nB = sqrtf(pB[t][0] * pB[t][0] + pB[t][1] * pB[t][1] + pB[t][2] * pB[t][2]);
    if (nA <= EPSV) zA |= 1 << t;
    if (nB <= EPSV) zB |= 1 << t;
    npA[t] = nA + EPSV; npB[t] = nB + EPSV;
    norm_s[sub * 2 + t][jc] = npA[t];
    norm_s[sub * 2 + t][jc + 64] = npB[t];
  }
  __syncthreads();

  float a2[2];
  { float bb = b1[jc]; a2[0] = bb; a2[1] = bb; }
  #pragma unroll 2
  for (int c = 0; c < 128; c += 4) {
    float w4[4];
    #pragma unroll
    for (int i = 0; i < 4; ++i) w4[i] = w1[(c + i) * 64 + jc];
    #pragma unroll
    for (int t = 0; t < 2; ++t) {
      float4 n4 = *(const float4*)&norm_s[sub * 2 + t][c];
      a2[t] += dot4(n4, w4);
    }
  }
  #pragma unroll
  for (int t = 0; t < 2; ++t)
    h_s[sub * 2 + t][jc] = a2[t] > 0.f ? a2[t] : NSL * a2[t];
  __syncthreads();

  float bnA[2], bnB[2];
  {
    float bA = b2[jc], bB = b2[jc + 64];
    #pragma unroll
    for (int t = 0; t < 2; ++t) { bnA[t] = bA + npA[t]; bnB[t] = bB + npB[t]; }
  }
  #pragma unroll 2
  for (int c = 0; c < 64; c += 4) {
    float wA[4], wB[4];
    #pragma unroll
    for (int i = 0; i < 4; ++i) {
      wA[i] = w2[(c + i) * 128 + jc];
      wB[i] = w2[(c + i) * 128 + jc + 64];
    }
    #pragma unroll
    for (int t = 0; t < 2; ++t) {
      float4 h4 = *(const float4*)&h_s[sub * 2 + t][c];
      bnA[t] += dot4(h4, wA);
      bnB[t] += dot4(h4, wB);
    }
  }

  #pragma unroll
  for (int t = 0; t < 2; ++t) {
    float rA = (zA >> t) & 1 ? 1.f : bnA[t] / npA[t];
    float rB = (zB >> t) & 1 ? 1.f : bnB[t] / npB[t];
    float* od = out + (size_t)(tokA + t) * 384;
    #pragma unroll
    for (int f = 0; f < 3; ++f) {
      od[f * 128 + jc]      = pA[t][f] * rA;
      od[f * 128 + jc + 64] = pB[t][f] * rB;
    }
  }
}

// ---------------------------------------------------------------------------
extern "C" void kernel_launch(void* const* d_in, const int* in_sizes, int n_in,
                              void* d_out, int out_size, void* d_ws, size_t ws_size,
                              hipStream_t stream) {
  const float* qfts   = (const float*)d_in[0];
  const float* kvfts  = (const float*)d_in[1];
  const float* w_q_in = (const float*)d_in[2];
  const float* q_w1   = (const float*)d_in[3];
  const float* q_b1   = (const float*)d_in[4];
  const float* q_w2   = (const float*)d_in[5];
  const float* q_b2   = (const float*)d_in[6];
  const float* w_kv_in= (const float*)d_in[7];
  const float* kv_w1  = (const float*)d_in[8];
  const float* kv_b1  = (const float*)d_in[9];
  const float* kv_w2  = (const float*)d_in[10];
  const float* kv_b2  = (const float*)d_in[11];
  const float* w_q    = (const float*)d_in[12];
  const float* w_k    = (const float*)d_in[13];
  const float* w_v    = (const float*)d_in[14];
  const float* w_out  = (const float*)d_in[15];
  const float* o_w1   = (const float*)d_in[16];
  const float* o_b1   = (const float*)d_in[17];
  const float* o_w2   = (const float*)d_in[18];
  const float* o_b2   = (const float*)d_in[19];

  unsigned short* QW = (unsigned short*)d_ws;
  unsigned short* KW = QW + 3145728;
  unsigned short* VW = KW + 3145728;
  float* Obuf = (float*)(VW + 3145728);
  // f scratch: q-branch uses Obuf (overwritten by attn later);
  // kv-branch uses d_out (overwritten by out_kernel later).
  float* fg_q  = Obuf;
  float* fg_kv = (float*)d_out;

  dim3 pg(BB * NN / TB, 2);
  pre_kernel<<<pg, 128, 0, stream>>>(qfts, kvfts,
                                     w_q_in, q_w1, q_b1, q_w2, q_b2,
                                     w_kv_in, kv_w1, kv_b1, kv_w2, kv_b2,
                                     w_q, w_k, w_v, fg_q, fg_kv, QW, KW, VW);
  dim3 ag(32, 16);
  attn_kernel<<<ag, 512, 0, stream>>>(QW, KW, VW, Obuf);
  out_kernel<<<BB * NN / TB, 128, 0, stream>>>(Obuf, w_out, o_w1, o_b1, o_w2, o_b2, (float*)d_out);
}

// Round 10
// 127.107 us; speedup vs baseline: 1.0647x; 1.0647x over previous
//
#include <hip/hip_runtime.h>
#include <math.h>

#define EPSV 1e-6f
#define NSL  0.2f
#define BB   2
#define NN   2048
#define HH   8
#define TB   4

typedef short bf16x8 __attribute__((ext_vector_type(8)));
typedef float f32x4  __attribute__((ext_vector_type(4)));

__device__ __forceinline__ unsigned short f2bf(float x) {
  union { float f; unsigned int u; } v; v.f = x;
  unsigned int r = v.u + 0x7FFF + ((v.u >> 16) & 1);
  return (unsigned short)(r >> 16);
}
__device__ __forceinline__ float bf2f(unsigned short h) {
  union { float f; unsigned int u; } v; v.u = ((unsigned int)h) << 16;
  return v.f;
}
__device__ __forceinline__ unsigned cvt_pk_bf16(float a, float b) {
  unsigned r;
  asm("v_cvt_pk_bf16_f32 %0, %1, %2" : "=v"(r) : "v"(a), "v"(b));
  return r;
}
__device__ __forceinline__ float dot4(float4 x, const float* w) {
  return x.x * w[0] + x.y * w[1] + x.z * w[2] + x.w * w[3];
}
__device__ __forceinline__ float leaky(float a) { return a > 0.f ? a : NSL * a; }

// Workspace fragment layouts (bf16 hi/lo planes):
// QW/KW per (hb, tile16): [hl 2][768]: c0=[lane64][8] @0, c1=[lane<32][8] @512
// VW per (hb, kc32, f):   [hl 2][512]: [lane64][8]

// ---------------------------------------------------------------------------
// pre: merged q/kv (blockIdx.y: 0=q, 1=kv). 4 tokens / 128 threads.
// Thread = 4 channels (c0, c0+32, c0+64, c0+96) x 1 token (tid>>5).
// x and f stay in LDS (broadcast reads, but only 3 per c-step now).
// Q scaled by 0.25*log2(e): softmax runs in exp2 domain.
// ---------------------------------------------------------------------------
__global__ __launch_bounds__(128) void pre_kernel(
    const float* __restrict__ qfts, const float* __restrict__ kvfts,
    const float* __restrict__ wq_in, const float* __restrict__ qw1, const float* __restrict__ qb1,
    const float* __restrict__ qw2, const float* __restrict__ qb2,
    const float* __restrict__ wkv_in, const float* __restrict__ kw1, const float* __restrict__ kb1,
    const float* __restrict__ kw2, const float* __restrict__ kb2,
    const float* __restrict__ w_q, const float* __restrict__ w_k, const float* __restrict__ w_v,
    unsigned short* __restrict__ QW, unsigned short* __restrict__ KW, unsigned short* __restrict__ VW)
{
  const bool is_kv = blockIdx.y != 0;
  const float* x_in = is_kv ? kvfts : qfts;
  const float* w_in = is_kv ? wkv_in : wq_in;
  const float* w1   = is_kv ? kw1 : qw1;
  const float* b1   = is_kv ? kb1 : qb1;
  const float* w2   = is_kv ? kw2 : qw2;
  const float* b2   = is_kv ? kb2 : qb2;
  const float* w_p  = is_kv ? w_k : w_q;
  unsigned short* FW = is_kv ? KW : QW;
  const float ln_sc = is_kv ? 1.f : 0.25f * 1.44269504088896f;

  const int t0 = blockIdx.x * TB;
  const int tid = threadIdx.x;
  const int tl  = tid >> 5;            // local token 0..3
  const int c0  = tid & 31;            // base channel; owns c0+32k, k=0..3
  const int tok = t0 + tl;

  __shared__ float xs[TB][192];
  __shared__ float norm_s[TB][128];
  __shared__ float h_s[TB][64];
  __shared__ float f_s[TB][3][128];

  {
    const float4* src = (const float4*)(x_in + (size_t)t0 * 192);
    float4* dst = (float4*)&xs[0][0];
    dst[tid] = src[tid];
    if (tid < 64) dst[128 + tid] = src[128 + tid];
  }
  __syncthreads();

  // ---- phase 1: input GEMM (K=64) -> p[f][k] ----
  float p[3][4] = {{0.f}};
  #pragma unroll 2
  for (int c = 0; c < 64; c += 4) {
    float w4[4][4];
    #pragma unroll
    for (int i = 0; i < 4; ++i)
      #pragma unroll
      for (int k = 0; k < 4; ++k)
        w4[i][k] = w_in[(c + i) * 128 + c0 + k * 32];
    #pragma unroll
    for (int f = 0; f < 3; ++f) {
      float4 xv = *(const float4*)&xs[tl][f * 64 + c];
      #pragma unroll
      for (int k = 0; k < 4; ++k)
        p[f][k] += xv.x * w4[0][k] + xv.y * w4[1][k] + xv.z * w4[2][k] + xv.w * w4[3][k];
    }
  }

  // ---- phase 2: norms ----
  float np[4]; int zm = 0;
  #pragma unroll
  for (int k = 0; k < 4; ++k) {
    float nn = sqrtf(p[0][k] * p[0][k] + p[1][k] * p[1][k] + p[2][k] * p[2][k]);
    if (nn <= EPSV) zm |= 1 << k;
    np[k] = nn + EPSV;
    norm_s[tl][c0 + k * 32] = np[k];
  }
  __syncthreads();

  // ---- phase 3: MLP1 (128->64): thread does 2 ch of its token ----
  {
    float a0 = b1[c0], a1 = b1[c0 + 32];
    #pragma unroll 2
    for (int c = 0; c < 128; c += 4) {
      float wa[4], wb[4];
      #pragma unroll
      for (int i = 0; i < 4; ++i) {
        wa[i] = w1[(c + i) * 64 + c0];
        wb[i] = w1[(c + i) * 64 + c0 + 32];
      }
      float4 n4 = *(const float4*)&norm_s[tl][c];
      a0 += dot4(n4, wa);
      a1 += dot4(n4, wb);
    }
    h_s[tl][c0]      = leaky(a0);
    h_s[tl][c0 + 32] = leaky(a1);
  }
  __syncthreads();

  // ---- phase 4: MLP2 (64->128) -> bn[k] ----
  float bn[4];
  #pragma unroll
  for (int k = 0; k < 4; ++k) bn[k] = b2[c0 + k * 32] + np[k];
  #pragma unroll 2
  for (int c = 0; c < 64; c += 4) {
    float w4[4][4];
    #pragma unroll
    for (int i = 0; i < 4; ++i)
      #pragma unroll
      for (int k = 0; k < 4; ++k)
        w4[i][k] = w2[(c + i) * 128 + c0 + k * 32];
    float4 h4 = *(const float4*)&h_s[tl][c];
    #pragma unroll
    for (int k = 0; k < 4; ++k)
      bn[k] += h4.x * w4[0][k] + h4.y * w4[1][k] + h4.z * w4[2][k] + h4.w * w4[3][k];
  }

  // ---- phase 5: ratio; write f to LDS ----
  #pragma unroll
  for (int k = 0; k < 4; ++k) {
    float r = (zm >> k) & 1 ? 1.f : bn[k] / np[k];
    #pragma unroll
    for (int f = 0; f < 3; ++f)
      f_s[tl][f][c0 + k * 32] = p[f][k] * r;
  }
  __syncthreads();

  // ---- phase 6: projections (K=128) ----
  float q[3][4] = {{0.f}};
  float v[3][4] = {{0.f}};
  #pragma unroll 1
  for (int c = 0; c < 128; c += 4) {
    float wk[4][4], wv[4][4];
    #pragma unroll
    for (int i = 0; i < 4; ++i)
      #pragma unroll
      for (int k = 0; k < 4; ++k) {
        wk[i][k] = w_p[(c + i) * 128 + c0 + k * 32];
        if (is_kv) wv[i][k] = w_v[(c + i) * 128 + c0 + k * 32];
      }
    #pragma unroll
    for (int f = 0; f < 3; ++f) {
      float4 fv = *(const float4*)&f_s[tl][f][c];
      #pragma unroll
      for (int k = 0; k < 4; ++k) {
        q[f][k] += fv.x * wk[0][k] + fv.y * wk[1][k] + fv.z * wk[2][k] + fv.w * wk[3][k];
        if (is_kv)
          v[f][k] += fv.x * wv[0][k] + fv.y * wv[1][k] + fv.z * wv[2][k] + fv.w * wv[3][k];
      }
    }
  }

  // ---- phase 7: EV layernorm (q/k) + fragment writes ----
  const int b = tok >> 11, n = tok & (NN - 1);
  const int row = n & 15;
  #pragma unroll
  for (int k = 0; k < 4; ++k) {
    float ss = q[0][k] * q[0][k] + q[1][k] * q[1][k] + q[2][k] * q[2][k];
    ss += __shfl_xor(ss, 1, 16);
    ss += __shfl_xor(ss, 2, 16);
    ss += __shfl_xor(ss, 4, 16);
    ss += __shfl_xor(ss, 8, 16);
    float inv = ln_sc / (sqrtf(ss * (1.f / 16.f)) + EPSV);
    const int ch = c0 + k * 32;
    const int hh = ch >> 4, dd = ch & 15;
    const int hb = hh * BB + b;
    const size_t base = (size_t)(hb * 128 + (n >> 4)) * 1536;
    #pragma unroll
    for (int f = 0; f < 3; ++f) {
      float val = q[f][k] * inv;
      int d = f * 16 + dd;
      int off;
      if (d < 32) off = ((d >> 3) * 16 + row) * 8 + (d & 7);
      else        off = 512 + (((d - 32) >> 3) * 16 + row) * 8 + ((d - 32) & 7);
      unsigned short hi = f2bf(val);
      FW[base + off] = hi;
      FW[base + 768 + off] = f2bf(val - bf2f(hi));
    }
    if (is_kv) {
      const int voff = (((n & 31) >> 3) * 16 + dd) * 8 + (n & 7);
      #pragma unroll
      for (int f = 0; f < 3; ++f) {
        const size_t vbase = (size_t)((hb * 64 + (n >> 5)) * 3 + f) * 1024;
        unsigned short hi = f2bf(v[f][k]);
        VW[vbase + voff] = hi;
        VW[vbase + 512 + voff] = f2bf(v[f][k] - bf2f(hi));
      }
    }
  }
}

// ---------------------------------------------------------------------------
// attention: MFMA flash, 4-way K-split, 32 q per wave (r7 measured-good).
// ---------------------------------------------------------------------------
#define THR 10.0f

__global__ __launch_bounds__(512, 4) void attn_kernel(
    const unsigned short* __restrict__ QW, const unsigned short* __restrict__ KW,
    const unsigned short* __restrict__ VW, float* __restrict__ Ob)
{
  const int lane = threadIdx.x & 63;
  const int w = threadIdx.x >> 6;
  const int qt = w & 1;
  const int kq = w >> 1;
  const int hb = blockIdx.y;
  const int tA = blockIdx.x * 4 + qt * 2;
  const int q = lane & 15, g = lane >> 4;

  __shared__ unsigned short plds[8][2][1152];
  float* comb = (float*)plds;

  bf16x8 qh0[2], ql0[2], qh1[2], ql1[2];
  #pragma unroll
  for (int qs = 0; qs < 2; ++qs) {
    const size_t qbase = (size_t)(hb * 128 + tA + qs) * 1536;
    qh0[qs] = *(const bf16x8*)(QW + qbase + lane * 8);
    ql0[qs] = *(const bf16x8*)(QW + qbase + 768 + lane * 8);
    qh1[qs] = (bf16x8){0,0,0,0,0,0,0,0};
    ql1[qs] = (bf16x8){0,0,0,0,0,0,0,0};
    if (lane < 32) {
      qh1[qs] = *(const bf16x8*)(QW + qbase + 512 + lane * 8);
      ql1[qs] = *(const bf16x8*)(QW + qbase + 768 + 512 + lane * 8);
    }
  }

  f32x4 o[2][3];
  #pragma unroll
  for (int qs = 0; qs < 2; ++qs)
    #pragma unroll
    for (int f = 0; f < 3; ++f) o[qs][f] = (f32x4){0.f, 0.f, 0.f, 0.f};
  float m[2] = {-INFINITY, -INFINITY}, l[2] = {0.f, 0.f};

  for (int T = kq * 8; T < kq * 8 + 8; ++T) {
    f32x4 sc[2][4];
    __builtin_amdgcn_s_setprio(1);
    #pragma unroll
    for (int st = 0; st < 4; ++st) {
      const size_t kb = (size_t)(hb * 128 + T * 4 + st) * 1536;
      bf16x8 kh0 = *(const bf16x8*)(KW + kb + lane * 8);
      bf16x8 kl0 = *(const bf16x8*)(KW + kb + 768 + lane * 8);
      bf16x8 kh1 = *(const bf16x8*)(KW + kb + 512 + lane * 8);
      bf16x8 kl1 = *(const bf16x8*)(KW + kb + 768 + 512 + lane * 8);
      #pragma unroll
      for (int qs = 0; qs < 2; ++qs) {
        f32x4 a = {0.f, 0.f, 0.f, 0.f};
        a = __builtin_amdgcn_mfma_f32_16x16x32_bf16(kh0, qh0[qs], a, 0, 0, 0);
        a = __builtin_amdgcn_mfma_f32_16x16x32_bf16(kh0, ql0[qs], a, 0, 0, 0);
        a = __builtin_amdgcn_mfma_f32_16x16x32_bf16(kl0, qh0[qs], a, 0, 0, 0);
        a = __builtin_amdgcn_mfma_f32_16x16x32_bf16(kh1, qh1[qs], a, 0, 0, 0);
        a = __builtin_amdgcn_mfma_f32_16x16x32_bf16(kh1, ql1[qs], a, 0, 0, 0);
        a = __builtin_amdgcn_mfma_f32_16x16x32_bf16(kl1, qh1[qs], a, 0, 0, 0);
        sc[qs][st] = a;
      }
    }
    __builtin_amdgcn_s_setprio(0);

    #pragma unroll
    for (int qs = 0; qs < 2; ++qs) {
      float tm = sc[qs][0][0];
      #pragma unroll
      for (int st = 0; st < 4; ++st)
        #pragma unroll
        for (int r = 0; r < 4; ++r) tm = fmaxf(tm, sc[qs][st][r]);
      tm = fmaxf(tm, __shfl_xor(tm, 16));
      tm = fmaxf(tm, __shfl_xor(tm, 32));
      if (__any(tm > m[qs] + THR)) {
        float mnew = fmaxf(m[qs], tm);
        float scl = __builtin_amdgcn_exp2f(m[qs] - mnew);
        l[qs] *= scl;
        #pragma unroll
        for (int f = 0; f < 3; ++f) {
          o[qs][f][0] *= scl; o[qs][f][1] *= scl;
          o[qs][f][2] *= scl; o[qs][f][3] *= scl;
        }
        m[qs] = mnew;
      }
      float lp = 0.f;
      #pragma unroll
      for (int st = 0; st < 4; ++st) {
        float p0 = __builtin_amdgcn_exp2f(sc[qs][st][0] - m[qs]);
        float p1 = __builtin_amdgcn_exp2f(sc[qs][st][1] - m[qs]);
        float p2 = __builtin_amdgcn_exp2f(sc[qs][st][2] - m[qs]);
        float p3 = __builtin_amdgcn_exp2f(sc[qs][st][3] - m[qs]);
        lp += (p0 + p1) + (p2 + p3);
        uint2 uh = {cvt_pk_bf16(p0, p1), cvt_pk_bf16(p2, p3)};
        *(uint2*)&plds[w][qs][q * 72 + st * 16 + g * 4] = uh;
      }
      lp += __shfl_xor(lp, 16);
      lp += __shfl_xor(lp, 32);
      l[qs] += lp;
    }

    asm volatile("s_waitcnt lgkmcnt(0)" ::: "memory");

    __builtin_amdgcn_s_setprio(1);
    #pragma unroll
    for (int c = 0; c < 2; ++c) {
      const int kc = T * 2 + c;
      bf16x8 pb[2];
      #pragma unroll
      for (int qs = 0; qs < 2; ++qs)
        pb[qs] = *(const bf16x8*)&plds[w][qs][q * 72 + c * 32 + g * 8];
      #pragma unroll
      for (int f = 0; f < 3; ++f) {
        const size_t vb = (size_t)((hb * 64 + kc) * 3 + f) * 1024;
        bf16x8 vh = *(const bf16x8*)(VW + vb + lane * 8);
        bf16x8 vl = *(const bf16x8*)(VW + vb + 512 + lane * 8);
        #pragma unroll
        for (int qs = 0; qs < 2; ++qs) {
          o[qs][f] = __builtin_amdgcn_mfma_f32_16x16x32_bf16(vh, pb[qs], o[qs][f], 0, 0, 0);
          o[qs][f] = __builtin_amdgcn_mfma_f32_16x16x32_bf16(vl, pb[qs], o[qs][f], 0, 0, 0);
        }
      }
    }
    __builtin_amdgcn_s_setprio(0);
  }

  #define SLOT(qt_, qs_, r_) (comb + ((((qt_) * 2 + (qs_)) * 2 + (r_)) * 64 + lane) * 14)
  __syncthreads();
  if (kq & 1) {
    #pragma unroll
    for (int qs = 0; qs < 2; ++qs) {
      float* cb = SLOT(qt, qs, kq >> 1);
      #pragma unroll
      for (int f = 0; f < 3; ++f)
        #pragma unroll
        for (int r = 0; r < 4; ++r) cb[f * 4 + r] = o[qs][f][r];
      cb[12] = m[qs]; cb[13] = l[qs];
    }
  }
  __syncthreads();
  if (!(kq & 1)) {
    #pragma unroll
    for (int qs = 0; qs < 2; ++qs) {
      const float* cb = SLOT(qt, qs, kq >> 1);
      float m1 = cb[12], l1 = cb[13];
      float mn = fmaxf(m[qs], m1);
      float s0 = __builtin_amdgcn_exp2f(m[qs] - mn);
      float s1 = __builtin_amdgcn_exp2f(m1 - mn);
      l[qs] = l[qs] * s0 + l1 * s1;
      #pragma unroll
      for (int f = 0; f < 3; ++f)
        #pragma unroll
        for (int r = 0; r < 4; ++r)
          o[qs][f][r] = o[qs][f][r] * s0 + cb[f * 4 + r] * s1;
      m[qs] = mn;
    }
  }
  __syncthreads();
  if (kq == 2) {
    #pragma unroll
    for (int qs = 0; qs < 2; ++qs) {
      float* cb = SLOT(qt, qs, 1);
      #pragma unroll
      for (int f = 0; f < 3; ++f)
        #pragma unroll
        for (int r = 0; r < 4; ++r) cb[f * 4 + r] = o[qs][f][r];
      cb[12] = m[qs]; cb[13] = l[qs];
    }
  }
  __syncthreads();
  if (kq == 0) {
    const int h_ = hb >> 1, b_ = hb & 1;
    #pragma unroll
    for (int qs = 0; qs < 2; ++qs) {
      const float* cb = SLOT(qt, qs, 1);
      float m1 = cb[12], l1 = cb[13];
      float mn = fmaxf(m[qs], m1);
      float s0 = __builtin_amdgcn_exp2f(m[qs] - mn);
      float s1 = __builtin_amdgcn_exp2f(m1 - mn);
      float invl = 1.f / (l[qs] * s0 + l1 * s1);
      const int n = (tA + qs) * 16 + q;
      #pragma unroll
      for (int f = 0; f < 3; ++f) {
        float4 st4 = {(o[qs][f][0] * s0 + cb[f * 4 + 0] * s1) * invl,
                      (o[qs][f][1] * s0 + cb[f * 4 + 1] * s1) * invl,
                      (o[qs][f][2] * s0 + cb[f * 4 + 2] * s1) * invl,
                      (o[qs][f][3] * s0 + cb[f * 4 + 3] * s1) * invl};
        *(float4*)&Ob[(((size_t)(b_ * NN + n)) * 3 + f) * 128 + h_ * 16 + g * 4] = st4;
      }
    }
  }
  #undef SLOT
}

// ---------------------------------------------------------------------------
// out: ev_nonlin(resi @ w_out). Thread = 4 ch x 1 token, resi in LDS.
// ---------------------------------------------------------------------------
__global__ __launch_bounds__(128) void out_kernel(
    const float* __restrict__ Ob, const float* __restrict__ w_out,
    const float* __restrict__ w1, const float* __restrict__ b1,
    const float* __restrict__ w2, const float* __restrict__ b2,
    float* __restrict__ out)
{
  const int t0 = blockIdx.x * TB;
  const int tid = threadIdx.x;
  const int tl  = tid >> 5;
  const int c0  = tid & 31;
  const int tok = t0 + tl;

  __shared__ float rs[TB][384];
  __shared__ float norm_s[TB][128];
  __shared__ float h_s[TB][64];

  {
    const float4* src = (const float4*)(Ob + (size_t)t0 * 384);
    float4* dst = (float4*)&rs[0][0];
    #pragma unroll
    for (int i = 0; i < 3; ++i) dst[tid + i * 128] = src[tid + i * 128];
  }
  __syncthreads();

  // proj (K=128)
  float p[3][4] = {{0.f}};
  #pragma unroll 2
  for (int c = 0; c < 128; c += 4) {
    float w4[4][4];
    #pragma unroll
    for (int i = 0; i < 4; ++i)
      #pragma unroll
      for (int k = 0; k < 4; ++k)
        w4[i][k] = w_out[(c + i) * 128 + c0 + k * 32];
    #pragma unroll
    for (int f = 0; f < 3; ++f) {
      float4 rv = *(const float4*)&rs[tl][f * 128 + c];
      #pragma unroll
      for (int k = 0; k < 4; ++k)
        p[f][k] += rv.x * w4[0][k] + rv.y * w4[1][k] + rv.z * w4[2][k] + rv.w * w4[3][k];
    }
  }

  float np[4]; int zm = 0;
  #pragma unroll
  for (int k = 0; k < 4; ++k) {
    float nn = sqrtf(p[0][k] * p[0][k] + p[1][k] * p[1][k] + p[2][k] * p[2][k]);
    if (nn <= EPSV) zm |= 1 << k;
    np[k] = nn + EPSV;
    norm_s[tl][c0 + k * 32] = np[k];
  }
  __syncthreads();

  {
    float a0 = b1[c0], a1 = b1[c0 + 32];
    #pragma unroll 2
    for (int c = 0; c < 128; c += 4) {
      float wa[4], wb[4];
      #pragma unroll
      for (int i = 0; i < 4; ++i) {
        wa[i] = w1[(c + i) * 64 + c0];
        wb[i] = w1[(c + i) * 64 + c0 + 32];
      }
      float4 n4 = *(const float4*)&norm_s[tl][c];
      a0 += dot4(n4, wa);
      a1 += dot4(n4, wb);
    }
    h_s[tl][c0]      = leaky(a0);
    h_s[tl][c0 + 32] = leaky(a1);
  }
  __syncthreads();

  float bn[4];
  #pragma unroll
  for (int k = 0; k < 4; ++k) bn[k] = b2[c0 + k * 32] + np[k];
  #pragma unroll 2
  for (int c = 0; c < 64; c += 4) {
    float w4[4][4];
    #pragma unroll
    for (int i = 0; i < 4; ++i)
      #pragma unroll
      for (int k = 0; k < 4; ++k)
        w4[i][k] = w2[(c + i) * 128 + c0 + k * 32];
    float4 h4 = *(const float4*)&h_s[tl][c];
    #pragma unroll
    for (int k = 0; k < 4; ++k)
      bn[k] += h4.x * w4[0][k] + h4.y * w4[1][k] + h4.z * w4[2][k] + h4.w * w4[3][k];
  }

  float* od = out + (size_t)tok * 384;
  #pragma unroll
  for (int k = 0; k < 4; ++k) {
    float r = (zm >> k) & 1 ? 1.f : bn[k] / np[k];
    #pragma unroll
    for (int f = 0; f < 3; ++f)
      od[f * 128 + c0 + k * 32] = p[f][k] * r;
  }
}

// ---------------------------------------------------------------------------
extern "C" void kernel_launch(void* const* d_in, const int* in_sizes, int n_in,
                              void* d_out, int out_size, void* d_ws, size_t ws_size,
                              hipStream_t stream) {
  const float* qfts   = (const float*)d_in[0];
  const float* kvfts  = (const float*)d_in[1];
  const float* w_q_in = (const float*)d_in[2];
  const float* q_w1   = (const float*)d_in[3];
  const float* q_b1   = (const float*)d_in[4];
  const float* q_w2   = (const float*)d_in[5];
  const float* q_b2   = (const float*)d_in[6];
  const float* w_kv_in= (const float*)d_in[7];
  const float* kv_w1  = (const float*)d_in[8];
  const float* kv_b1  = (const float*)d_in[9];
  const float* kv_w2  = (const float*)d_in[10];
  const float* kv_b2  = (const float*)d_in[11];
  const float* w_q    = (const float*)d_in[12];
  const float* w_k    = (const float*)d_in[13];
  const float* w_v    = (const float*)d_in[14];
  const float* w_out  = (const float*)d_in[15];
  const float* o_w1   = (const float*)d_in[16];
  const float* o_b1   = (const float*)d_in[17];
  const float* o_w2   = (const float*)d_in[18];
  const float* o_b2   = (const float*)d_in[19];

  unsigned short* QW = (unsigned short*)d_ws;
  unsigned short* KW = QW + 3145728;
  unsigned short* VW = KW + 3145728;
  float* Obuf = (float*)(VW + 3145728);

  dim3 pg(BB * NN / TB, 2);
  pre_kernel<<<pg, 128, 0, stream>>>(qfts, kvfts,
                                     w_q_in, q_w1, q_b1, q_w2, q_b2,
                                     w_kv_in, kv_w1, kv_b1, kv_w2, kv_b2,
                                     w_q, w_k, w_v, QW, KW, VW);
  dim3 ag(32, 16);
  attn_kernel<<<ag, 512, 0, stream>>>(QW, KW, VW, Obuf);
  out_kernel<<<BB * NN / TB, 128, 0, stream>>>(Obuf, w_out, o_w1, o_b1, o_w2, o_b2, (float*)d_out);
}